// Round 7
// baseline (273.611 us; speedup 1.0000x reference)
//
#include <hip/hip_runtime.h>

// SparseGlobalPool: segment-mean of features [N, C=128] over batch_ids in [0, B=32).
// out[b][c] = mean of features[i][c] where batch_ids[i]==b, 0 if empty.
//
// ws layout: float sums[B*C] ; unsigned counts[B]   (4128 dwords = 16.5 KB)
//
// Round-1/2: LDS float ATOMICS serialize on the LDS atomic pipe (1285us). Banned.
// Round-4/5: register accumulators behind a 32-case switch -> scratch array
//   (rule #20), 136MB spill traffic, ~1100us. Banned.
// Round-6: per-wave PRIVATE LDS accumulator, no atomics in the loop -> 220us
//   (~75% of achievable BW). This round: latency-hiding tuning only —
//   WPB 4->2 (32KB LDS/block -> 5 blocks/CU = 10 waves/CU, 160KB LDS fully
//   used) and RPC 4->8 (4KB in flight/wave -> 40KB/CU, Little's law >> 10KB).

constexpr int CH = 128;       // channels
constexpr int BATCH = 32;     // segments
constexpr int WPB = 2;        // waves per block (128 threads)
constexpr int RPC = 8;        // rows per chunk

__global__ __launch_bounds__(512) void sgp_zero(float* ws, int n) {
    int i = blockIdx.x * blockDim.x + threadIdx.x;
    if (i < n) ws[i] = 0.0f;   // bit-pattern 0 also zeroes the uint counts
}

__global__ __launch_bounds__(128, 2) void sgp_accum(const float2* __restrict__ feat2,
                                                    const int* __restrict__ bid,
                                                    float* __restrict__ gsum,
                                                    unsigned int* __restrict__ gcnt,
                                                    int N) {
    // Per-wave private accumulator: acc[wave][seg][lane] (float2 = 2 channels).
    // 2 waves x 32 segs x 64 lanes x 8B = 32768 B -> 5 blocks/CU (LDS-limited).
    __shared__ float2 acc[WPB][BATCH][64];

    const int tid  = threadIdx.x;
    const int lane = tid & 63;
    const int wib  = tid >> 6;    // wave index in block

    for (int i = tid; i < WPB * BATCH * 64; i += 128)
        (&acc[0][0][0])[i] = make_float2(0.0f, 0.0f);
    __syncthreads();

    const int w  = __builtin_amdgcn_readfirstlane((int)(blockIdx.x * WPB + wib));
    const int NW = gridDim.x * WPB;       // total waves
    const int F  = N / RPC;               // full chunks

    unsigned mycnt = 0u;                  // lane b counts rows with bid==b

    float2 v[RPC];
    int    b4[RPC];
    int c = w;
    if (c < F) {
        #pragma unroll
        for (int j = 0; j < RPC; ++j) {
            v[j]  = feat2[(size_t)(RPC * c + j) * 64 + lane];
            b4[j] = bid[RPC * c + j];
        }
    }
    while (c < F) {
        const int cn = c + NW;
        float2 nv[RPC];
        int    nb[RPC];
        if (cn < F) {
            // prefetch next chunk before touching LDS (hides HBM latency)
            #pragma unroll
            for (int j = 0; j < RPC; ++j) {
                nv[j] = feat2[(size_t)(RPC * cn + j) * 64 + lane];
                nb[j] = bid[RPC * cn + j];
            }
        }
        // process current chunk: plain LDS RMW, strictly in program order so
        // same-segment rows within the chunk accumulate correctly (DS ops from
        // one wave execute in order; compiler can't reorder across may-alias).
        #pragma unroll
        for (int j = 0; j < RPC; ++j) {
            const int b = __builtin_amdgcn_readfirstlane(b4[j]);
            float2 o = acc[wib][b][lane];
            o.x += v[j].x;
            o.y += v[j].y;
            acc[wib][b][lane] = o;
            mycnt += (lane == b) ? 1u : 0u;
        }
        if (cn < F) {
            #pragma unroll
            for (int j = 0; j < RPC; ++j) { v[j] = nv[j]; b4[j] = nb[j]; }
        }
        c = cn;
    }
    // tail rows (N % RPC), handled by wave 0 only
    if (w == 0) {
        for (int r = F * RPC; r < N; ++r) {
            const int b = __builtin_amdgcn_readfirstlane(bid[r]);
            const float2 t = feat2[(size_t)r * 64 + lane];
            float2 o = acc[wib][b][lane];
            o.x += t.x;
            o.y += t.y;
            acc[wib][b][lane] = o;
            mycnt += (lane == b) ? 1u : 0u;
        }
    }

    // counts: one wave-op per wave, 32 distinct addresses
    if (lane < BATCH) atomicAdd(&gcnt[lane], mycnt);

    __syncthreads();

    // block-reduce the 2 wave-regions and flush: 2048 float2 entries, 128 thr
    for (int e = tid; e < BATCH * 64; e += 128) {
        const int seg = e >> 6;
        const int ln  = e & 63;
        float2 s  = acc[0][seg][ln];
        float2 t1 = acc[1][seg][ln];
        s.x += t1.x;
        s.y += t1.y;
        unsafeAtomicAdd(&gsum[seg * CH + ln * 2],     s.x);
        unsafeAtomicAdd(&gsum[seg * CH + ln * 2 + 1], s.y);
    }
}

__global__ __launch_bounds__(256) void sgp_final(const float* __restrict__ gsum,
                                                 const unsigned int* __restrict__ gcnt,
                                                 float* __restrict__ out) {
    int idx = blockIdx.x * blockDim.x + threadIdx.x;
    if (idx < BATCH * CH) {
        const unsigned int c = gcnt[idx >> 7];
        out[idx] = (c > 0u) ? gsum[idx] / (float)c : 0.0f;
    }
}

extern "C" void kernel_launch(void* const* d_in, const int* in_sizes, int n_in,
                              void* d_out, int out_size, void* d_ws, size_t ws_size,
                              hipStream_t stream) {
    const float2* feat2 = (const float2*)d_in[0];
    const int* bid      = (const int*)d_in[1];
    const int N = in_sizes[1];

    float* gsum        = (float*)d_ws;
    unsigned int* gcnt = (unsigned int*)((char*)d_ws + BATCH * CH * sizeof(float));

    const int ws_dwords = BATCH * CH + BATCH;  // 4128
    sgp_zero<<<(ws_dwords + 511) / 512, 512, 0, stream>>>((float*)d_ws, ws_dwords);

    // 1280 blocks x 128 thr = 2560 waves; 32KB LDS/block -> 5 blocks/CU
    // (10 waves/CU, 160KB LDS), RPC=8 -> 4KB in flight/wave = 40KB/CU.
    sgp_accum<<<1280, 128, 0, stream>>>(feat2, bid, gsum, gcnt, N);

    sgp_final<<<(BATCH * CH + 255) / 256, 256, 0, stream>>>(gsum, gcnt, (float*)d_out);
}

// Round 8
// 186.997 us; speedup vs baseline: 1.4632x; 1.4632x over previous
//
#include <hip/hip_runtime.h>

// SparseGlobalPool: segment-mean of features [N, C=128] over batch_ids in [0, B=32).
// out[b][c] = mean of features[i][c] where batch_ids[i]==b, 0 if empty.
//
// ws layout: float sums[B*C] ; unsigned counts[B]   (4128 dwords = 16.5 KB)
//
// Round-1/2: LDS float ATOMICS serialize on the LDS atomic pipe (1285us). Banned.
// Round-4/5: register accumulators behind a 32-case switch -> scratch array
//   (rule #20), 136MB spill traffic, ~1100us. Banned.
// Round-6: per-wave PRIVATE LDS accumulator, WPB=4/RPC=4/grid 512 -> 220us
//   (~4.8 TB/s effective, 75% of achievable).
// Round-7: WPB=2/RPC=8/grid 1280 -> 274us. 5x32KB = exactly 160KB; any LDS
//   reservation -> only 4 blocks/CU resident -> 256-block straggler tail
//   (+25%, matches). Residency-exact grids only.
// This round: round-6 shell EXACTLY (WPB=4, 256thr, 64KB LDS, grid 512 = 2
//   blocks/CU guaranteed), single change RPC 4->8 (4KB in flight per wave,
//   ~32KB/CU outstanding) to beat loaded HBM latency. launch_bounds(256,2)
//   so ~80 live VGPRs don't trigger an 8-waves/EU spill target.

constexpr int CH = 128;       // channels
constexpr int BATCH = 32;     // segments
constexpr int WPB = 4;        // waves per block (256 threads)
constexpr int RPC = 8;        // rows per chunk

__global__ __launch_bounds__(512) void sgp_zero(float* ws, int n) {
    int i = blockIdx.x * blockDim.x + threadIdx.x;
    if (i < n) ws[i] = 0.0f;   // bit-pattern 0 also zeroes the uint counts
}

__global__ __launch_bounds__(256, 2) void sgp_accum(const float2* __restrict__ feat2,
                                                    const int* __restrict__ bid,
                                                    float* __restrict__ gsum,
                                                    unsigned int* __restrict__ gcnt,
                                                    int N) {
    // Per-wave private accumulator: acc[wave][seg][lane] (float2 = 2 channels).
    // 4 waves x 32 segs x 64 lanes x 8B = 65536 B -> 2 blocks/CU (LDS-limited).
    __shared__ float2 acc[WPB][BATCH][64];

    const int tid  = threadIdx.x;
    const int lane = tid & 63;
    const int wib  = tid >> 6;    // wave index in block

    for (int i = tid; i < WPB * BATCH * 64; i += 256)
        (&acc[0][0][0])[i] = make_float2(0.0f, 0.0f);
    __syncthreads();

    const int w  = __builtin_amdgcn_readfirstlane((int)(blockIdx.x * WPB + wib));
    const int NW = gridDim.x * WPB;       // total waves
    const int F  = N / RPC;               // full chunks

    unsigned mycnt = 0u;                  // lane b counts rows with bid==b

    float2 v[RPC];
    int    b4[RPC];
    int c = w;
    if (c < F) {
        #pragma unroll
        for (int j = 0; j < RPC; ++j) {
            v[j]  = feat2[(size_t)(RPC * c + j) * 64 + lane];
            b4[j] = bid[RPC * c + j];
        }
    }
    while (c < F) {
        const int cn = c + NW;
        float2 nv[RPC];
        int    nb[RPC];
        if (cn < F) {
            // prefetch next chunk before touching LDS (hides HBM latency)
            #pragma unroll
            for (int j = 0; j < RPC; ++j) {
                nv[j] = feat2[(size_t)(RPC * cn + j) * 64 + lane];
                nb[j] = bid[RPC * cn + j];
            }
        }
        // process current chunk: plain LDS RMW, strictly in program order so
        // same-segment rows within the chunk accumulate correctly (same-wave
        // DS ops execute in order; compiler can't reorder across may-alias).
        #pragma unroll
        for (int j = 0; j < RPC; ++j) {
            const int b = __builtin_amdgcn_readfirstlane(b4[j]);
            float2 o = acc[wib][b][lane];
            o.x += v[j].x;
            o.y += v[j].y;
            acc[wib][b][lane] = o;
            mycnt += (lane == b) ? 1u : 0u;
        }
        if (cn < F) {
            #pragma unroll
            for (int j = 0; j < RPC; ++j) { v[j] = nv[j]; b4[j] = nb[j]; }
        }
        c = cn;
    }
    // tail rows (N % RPC), handled by wave 0 only
    if (w == 0) {
        for (int r = F * RPC; r < N; ++r) {
            const int b = __builtin_amdgcn_readfirstlane(bid[r]);
            const float2 t = feat2[(size_t)r * 64 + lane];
            float2 o = acc[wib][b][lane];
            o.x += t.x;
            o.y += t.y;
            acc[wib][b][lane] = o;
            mycnt += (lane == b) ? 1u : 0u;
        }
    }

    // counts: one wave-op per wave, 32 distinct addresses
    if (lane < BATCH) atomicAdd(&gcnt[lane], mycnt);

    __syncthreads();

    // block-reduce the 4 wave-regions and flush: 2048 float2 entries, 256 thr
    for (int e = tid; e < BATCH * 64; e += 256) {
        const int seg = e >> 6;
        const int ln  = e & 63;
        float2 s  = acc[0][seg][ln];
        float2 t1 = acc[1][seg][ln];
        float2 t2 = acc[2][seg][ln];
        float2 t3 = acc[3][seg][ln];
        s.x += t1.x + t2.x + t3.x;
        s.y += t1.y + t2.y + t3.y;
        unsafeAtomicAdd(&gsum[seg * CH + ln * 2],     s.x);
        unsafeAtomicAdd(&gsum[seg * CH + ln * 2 + 1], s.y);
    }
}

__global__ __launch_bounds__(256) void sgp_final(const float* __restrict__ gsum,
                                                 const unsigned int* __restrict__ gcnt,
                                                 float* __restrict__ out) {
    int idx = blockIdx.x * blockDim.x + threadIdx.x;
    if (idx < BATCH * CH) {
        const unsigned int c = gcnt[idx >> 7];
        out[idx] = (c > 0u) ? gsum[idx] / (float)c : 0.0f;
    }
}

extern "C" void kernel_launch(void* const* d_in, const int* in_sizes, int n_in,
                              void* d_out, int out_size, void* d_ws, size_t ws_size,
                              hipStream_t stream) {
    const float2* feat2 = (const float2*)d_in[0];
    const int* bid      = (const int*)d_in[1];
    const int N = in_sizes[1];

    float* gsum        = (float*)d_ws;
    unsigned int* gcnt = (unsigned int*)((char*)d_ws + BATCH * CH * sizeof(float));

    const int ws_dwords = BATCH * CH + BATCH;  // 4128
    sgp_zero<<<(ws_dwords + 511) / 512, 512, 0, stream>>>((float*)d_ws, ws_dwords);

    // 512 blocks x 256 thr = 2048 waves; 64KB LDS/block -> exactly 2 blocks/CU
    // resident (8 waves/CU), RPC=8 prefetch -> ~32KB/CU of HBM loads in flight.
    sgp_accum<<<512, 256, 0, stream>>>(feat2, bid, gsum, gcnt, N);

    sgp_final<<<(BATCH * CH + 255) / 256, 256, 0, stream>>>(gsum, gcnt, (float*)d_out);
}